// Round 9
// baseline (761.729 us; speedup 1.0000x reference)
//
#include <hip/hip_runtime.h>
#include <math.h>

// RG-LRU single-pass: B=4, L=8192, W=1024, H=8, bw=128.
#define NB 4
#define NL 8192
#define NW 1024
#define NH 8
#define BWID 128
#define POWERF 8.0f

#define TM 64                 // timesteps per block == scan chunk
#define NRC (NL / TM)         // 128 chunks per sequence
#define NCHAIN (NB * NH)      // 32 independent scan chains
#define NBLK (NRC * NCHAIN)   // 4096 blocks

typedef __attribute__((ext_vector_type(8))) short bf16x8;          // MFMA A/B frag
typedef __attribute__((ext_vector_type(8))) unsigned short u16x8;  // raw 16B move
typedef __attribute__((ext_vector_type(4))) float f32x4;           // MFMA C/D frag

__device__ __forceinline__ unsigned short bf_hi(float f) {
  return (unsigned short)(__float_as_uint(f) >> 16);  // truncate to bf16
}
__device__ __forceinline__ float bf_f(unsigned short h) {
  return __uint_as_float(((unsigned)h) << 16);
}

// ---------------- prep: W^T bf16 hi/lo, softplus(a_param), zero sync state --
// wt layout: [mat(2)][split(2)][h(8)][col(128)][k(128)] ushort (1 MB total).
// carry layout: [vbid(4096)][chan(128)][2] u64 — word0 = inclusive
// (tag = hi-word nonzero), word1 = local (tag = sign bit of A field). 8 MB.
__global__ void prep_kernel(const float* __restrict__ w_in,
                            const float* __restrict__ w_a,
                            const float* __restrict__ a_param,
                            unsigned short* __restrict__ wt,
                            float* __restrict__ sp,
                            unsigned long long* __restrict__ carry,
                            int* __restrict__ ticket) {
  const int gtid = blockIdx.x * 256 + threadIdx.x;  // 0..262143
  const int k   = gtid & 127;
  const int col = (gtid >> 7) & 127;
  const int hh  = (gtid >> 14) & 7;
  const int mat = gtid >> 17;
  const float* src = mat ? w_a : w_in;
  const float v = src[((size_t)hh * 128 + k) * 128 + col];  // W[h][k][col]
  const unsigned short hi = bf_hi(v);
  const unsigned short lo = bf_hi(v - bf_f(hi));
  wt[(((size_t)(mat * 2 + 0) * 8 + hh) * 128 + col) * 128 + k] = hi;
  wt[(((size_t)(mat * 2 + 1) * 8 + hh) * 128 + col) * 128 + k] = lo;
  if (gtid < NW) sp[gtid] = log1pf(expf(a_param[gtid]));
  const size_t ci = (size_t)gtid * 4;   // zero NBLK*128*2 words (8 MB)
  carry[ci] = 0ull;
  carry[ci + 1] = 0ull;
  carry[ci + 2] = 0ull;
  carry[ci + 3] = 0ull;
  if (gtid == 0) *ticket = 0;
}

// ---------------- fused: MFMA gates + segmented scan + lookback carry -------
// vs R8: (1) X never touches LDS — A-frags are a pure per-thread partition of
// the tile, loaded straight from global (2 float4 per frag, line-coalesced
// across the g-groups) and hi/lo-split in registers, prefetched one k-tile
// ahead; epilogue xv re-reads exact fp32 from the L2-hot tile. (2) W is
// double-buffered (2x16 KB) -> ONE barrier per phase (8 vs 16). (3) LDS
// 48->32 KB -> 4 blocks/CU. Carry protocol identical to R8.
// Phase p (0..7): matrix m=p&1, k-tile j=p>>1; stage W(p+1) into buf^1 while
// computing on buf; A-frags converted at m=0, reused at m=1.
__global__ __launch_bounds__(256, 4)
void fused_kernel(const float* __restrict__ x,
                  const unsigned short* __restrict__ wt,
                  const float* __restrict__ sp,
                  const float* __restrict__ b_in,
                  const float* __restrict__ b_a,
                  float* __restrict__ out,
                  int* __restrict__ ticket,
                  unsigned long long* __restrict__ carry) {
  __shared__ char smem[32768];
  char* const pW0 = smem;            // 16 KB [col(128)][split(2)][kk(32)] swz
  char* const pW1 = smem + 16384;    // 16 KB (double buffer)
  char* const pSeg = smem;           // 16 KB f32x2 [col][seg(16)] (over pW0)

  const int tid  = threadIdx.x;
  // ---- ticket: decouples work-id from dispatch order ----
  if (tid == 0) *(int*)smem = atomicAdd(ticket, 1);
  __syncthreads();
  const int vbid = *(const int*)smem;
  __syncthreads();                   // vbid read by all before smem reuse
  const int rc = vbid >> 5;          // chunk index (layer-major: no deadlock)
  const int bh = vbid & 31;
  const int b  = bh >> 3;
  const int h  = bh & 7;

  const int lane = tid & 63;
  const int wid  = tid >> 6;
  const int g  = lane >> 4;   // k-group 0..3
  const int ln = lane & 15;
  const int wr = wid >> 1;    // row half (32 rows)
  const int wc = wid & 1;     // col half (64 cols)

  const size_t xbase = ((size_t)b * NL + (size_t)rc * TM) * NW + h * BWID;

  // ---- W stage addressing: 1024 16B chunks/phase = 4/thread ----
  int wsoff[4], wdoff[4];
#pragma unroll
  for (int i = 0; i < 4; ++i) {
    const int chunk = tid + 256 * i;   // 0..1023
    const int split = chunk >> 9;      // 0:hi 1:lo
    const int rem = chunk & 511;
    const int col = rem >> 2;
    const int kk8 = (rem & 3) * 8;
    wsoff[i] = split * 131072 + h * 16384 + col * 128 + kk8;  // +m*262144+j*32
    wdoff[i] = col * 128 + ((split * 64 + kk8 * 2) ^ ((col & 7) << 4));
  }

  // ---- A-frag source pointers: own rows, own k-slice (g*8) ----
  const float* const xr0 = x + xbase + (size_t)(wr * 32 + ln) * NW + g * 8;
  const float* const xr1 = xr0 + 16 * NW;

  // ---- prologue: load W(0), x(j=0); stage W(0); load W(1) ----
  u16x8 wreg[4];
#pragma unroll
  for (int i = 0; i < 4; ++i) wreg[i] = *(const u16x8*)(wt + wsoff[i]);
  float4 xf[2][2];
  xf[0][0] = *(const float4*)(xr0);
  xf[0][1] = *(const float4*)(xr0 + 4);
  xf[1][0] = *(const float4*)(xr1);
  xf[1][1] = *(const float4*)(xr1 + 4);
#pragma unroll
  for (int i = 0; i < 4; ++i) *(u16x8*)(pW0 + wdoff[i]) = wreg[i];  // W(0)
#pragma unroll
  for (int i = 0; i < 4; ++i)
    wreg[i] = *(const u16x8*)(wt + wsoff[i] + 262144);              // W(1)

  f32x4 accx[2][4], acca[2][4];
#pragma unroll
  for (int rt = 0; rt < 2; ++rt)
#pragma unroll
    for (int ct = 0; ct < 4; ++ct) {
      accx[rt][ct] = (f32x4){0.f, 0.f, 0.f, 0.f};
      acca[rt][ct] = (f32x4){0.f, 0.f, 0.f, 0.f};
    }

  const int csw = (ln & 7) << 4;     // B-frag swizzle (col&7 == ln&7)
  const int gk  = g * 16;
  bf16x8 Ah[2], Al[2];

#pragma unroll 1
  for (int p = 0; p < 8; ++p) {
    const int m = p & 1;
    const int j = p >> 1;
    __syncthreads();                 // buf[p&1] = W(p) ready; buf^1 free
    char* const pr = m ? pW1 : pW0;
    char* const pw = m ? pW0 : pW1;
    if (p < 7) {                     // stage W(p+1) into the other buffer
#pragma unroll
      for (int i = 0; i < 4; ++i) *(u16x8*)(pw + wdoff[i]) = wreg[i];
    }
    if (p < 6) {                     // load W(p+2) for next stage
      const int so = (((p + 2) & 1) ? 262144 : 0) + ((p + 2) >> 1) * 32;
#pragma unroll
      for (int i = 0; i < 4; ++i)
        wreg[i] = *(const u16x8*)(wt + wsoff[i] + so);
    }
    if (m == 0) {
      // convert this k-tile's A-frags from fp32 regs (hi/lo split)
#pragma unroll
      for (int rt = 0; rt < 2; ++rt) {
#pragma unroll
        for (int q = 0; q < 2; ++q) {
#pragma unroll
          for (int e = 0; e < 4; ++e) {
            const float f = xf[rt][q][e];
            const unsigned short hi = bf_hi(f);
            Ah[rt][q * 4 + e] = (short)hi;
            Al[rt][q * 4 + e] = (short)bf_hi(f - bf_f(hi));
          }
        }
      }
      if (j < 3) {                   // prefetch next k-tile's x
        const int ko = (j + 1) * 32;
        xf[0][0] = *(const float4*)(xr0 + ko);
        xf[0][1] = *(const float4*)(xr0 + ko + 4);
        xf[1][0] = *(const float4*)(xr1 + ko);
        xf[1][1] = *(const float4*)(xr1 + ko + 4);
      }
    }
    f32x4* acc = m ? acca[0] : accx[0];  // [rt][ct] flattened: rt*4+ct
#pragma unroll
    for (int ct = 0; ct < 4; ++ct) {
      const int cb = (wc * 64 + ct * 16 + ln) * 128;
      const bf16x8 Bh = *(const bf16x8*)(pr + cb + ((gk) ^ csw));
      const bf16x8 Bl = *(const bf16x8*)(pr + cb + ((64 + gk) ^ csw));
#pragma unroll
      for (int rt = 0; rt < 2; ++rt) {
        acc[rt * 4 + ct] = __builtin_amdgcn_mfma_f32_16x16x32_bf16(Ah[rt], Bh, acc[rt * 4 + ct], 0, 0, 0);
        acc[rt * 4 + ct] = __builtin_amdgcn_mfma_f32_16x16x32_bf16(Al[rt], Bh, acc[rt * 4 + ct], 0, 0, 0);
        acc[rt * 4 + ct] = __builtin_amdgcn_mfma_f32_16x16x32_bf16(Ah[rt], Bl, acc[rt * 4 + ct], 0, 0, 0);
      }
    }
  }
  // after the loop: pW0 last read at phase 6 (barrier-7 separated) -> free.

  // ---- gates into registers; xv re-read exact fp32 from L2-hot tile ----
  float av_sav[2][4][4], xn_sav[2][4][4];
#pragma unroll
  for (int ct = 0; ct < 4; ++ct) {
    const int col = wc * 64 + ct * 16 + ln;
    const float bi  = b_in[h * BWID + col];
    const float ba  = b_a[h * BWID + col];
    const float spv = sp[h * BWID + col];
#pragma unroll
    for (int rt = 0; rt < 2; ++rt) {
#pragma unroll
      for (int r = 0; r < 4; ++r) {
        const int row = wr * 32 + rt * 16 + g * 4 + r;  // C/D layout (m89)
        const float zx = accx[rt][ct][r] + bi;
        const float za = acca[rt][ct][r] + ba;
        const float xv = x[xbase + (size_t)row * NW + col];
        const float gx = __builtin_amdgcn_rcpf(1.f + __expf(-zx));
        const float ga = __builtin_amdgcn_rcpf(1.f + __expf(-za));
        const float la = -POWERF * ga * spv;
        const float av = __expf(la);
        const float asq = av * av;         // == exp(2*la) to ~1 ulp
        av_sav[rt][ct][r] = av;
        xn_sav[rt][ct][r] = xv * gx * sqrtf(fmaxf(1.f - asq, 0.f));
      }
    }
  }

  // ---- segment partials (4 consecutive timesteps each) -> pSeg ----
#pragma unroll
  for (int ct = 0; ct < 4; ++ct) {
    const int col = wc * 64 + ct * 16 + ln;
#pragma unroll
    for (int rt = 0; rt < 2; ++rt) {
      float A4 = 1.f, h4 = 0.f;
#pragma unroll
      for (int r = 0; r < 4; ++r) {
        h4 = fmaf(av_sav[rt][ct][r], h4, xn_sav[rt][ct][r]);
        A4 *= av_sav[rt][ct][r];
      }
      const int s = wr * 8 + rt * 4 + g;   // time-ordered segment index
      *(float2*)(pSeg + col * 128 + ((s * 8) ^ ((col & 15) << 3))) =
          make_float2(A4, h4);
    }
  }
  __syncthreads();

  // ---- scan threads: local compose, publish local, lookback, publish incl --
  if (tid < 128) {
    const int w = tid;
    float As[16], hs[16];
#pragma unroll
    for (int s = 0; s < 16; ++s) {
      const float2 v =
          *(const float2*)(pSeg + w * 128 + ((s * 8) ^ ((w & 15) << 3)));
      As[s] = v.x;
      hs[s] = v.y;
    }
    float Atot = 1.f, hloc = 0.f;
#pragma unroll
    for (int s = 0; s < 16; ++s) {
      hloc = fmaf(As[s], hloc, hs[s]);
      Atot *= As[s];
    }
    const size_t cbase = ((size_t)vbid * 128 + w) * 2;
    __hip_atomic_store(carry + cbase + 1,
                       ((unsigned long long)__float_as_uint(-Atot) << 32) |
                           (unsigned long long)__float_as_uint(hloc),
                       __ATOMIC_RELAXED, __HIP_MEMORY_SCOPE_AGENT);

    float hprev = 0.f;
    if (rc > 0) {
      float P = 1.f, q = 0.f;
      int j = vbid - NCHAIN;
      int spins = 0;
      while (true) {
        const size_t jb = ((size_t)j * 128 + w) * 2;
        const unsigned long long wi = __hip_atomic_load(
            carry + jb, __ATOMIC_RELAXED, __HIP_MEMORY_SCOPE_AGENT);
        if (wi >> 32) {               // inclusive ready
          hprev = fmaf(P, __uint_as_float((unsigned)wi), q);
          break;
        }
        const unsigned long long wl = __hip_atomic_load(
            carry + jb + 1, __ATOMIC_RELAXED, __HIP_MEMORY_SCOPE_AGENT);
        if (wl >> 63) {               // local ready: compose, step back
          const float Aj = -__uint_as_float((unsigned)(wl >> 32));
          const float hj = __uint_as_float((unsigned)wl);
          q = fmaf(P, hj, q);
          P *= Aj;
          if (j < NCHAIN) { hprev = q; break; }   // hit layer 0
          j -= NCHAIN;
          continue;
        }
        __builtin_amdgcn_s_sleep(1);
        if (++spins > (1 << 18)) { hprev = q; break; }  // poison, never hang
      }
    }
    const float Hm = fmaf(Atot, hprev, hloc);
    __hip_atomic_store(carry + cbase,
                       (1ull << 32) | (unsigned long long)__float_as_uint(Hm),
                       __ATOMIC_RELAXED, __HIP_MEMORY_SCOPE_AGENT);

    float p = hprev;                      // exclusive prefix per segment
#pragma unroll
    for (int s = 0; s < 16; ++s) {
      *(float*)(pSeg + w * 128 + ((s * 8) ^ ((w & 15) << 3))) = p;
      p = fmaf(As[s], p, hs[s]);
    }
  }
  __syncthreads();

  // ---- owners: rescan 4 rows from prefix, store out from regs ----
#pragma unroll
  for (int ct = 0; ct < 4; ++ct) {
    const int col = wc * 64 + ct * 16 + ln;
#pragma unroll
    for (int rt = 0; rt < 2; ++rt) {
      const int s = wr * 8 + rt * 4 + g;
      float hh =
          *(const float*)(pSeg + col * 128 + ((s * 8) ^ ((col & 15) << 3)));
#pragma unroll
      for (int r = 0; r < 4; ++r) {
        hh = fmaf(av_sav[rt][ct][r], hh, xn_sav[rt][ct][r]);
        out[xbase + (size_t)(wr * 32 + rt * 16 + g * 4 + r) * NW + col] = hh;
      }
    }
  }
}

extern "C" void kernel_launch(void* const* d_in, const int* in_sizes, int n_in,
                              void* d_out, int out_size, void* d_ws, size_t ws_size,
                              hipStream_t stream) {
  const float* x       = (const float*)d_in[0];
  const float* a_param = (const float*)d_in[1];
  const float* w_in    = (const float*)d_in[2];
  const float* b_in    = (const float*)d_in[3];
  const float* w_a     = (const float*)d_in[4];
  const float* b_a     = (const float*)d_in[5];
  float* out = (float*)d_out;

  // Workspace (~9.3 MB): carry[4096][128][2] u64 @0 (8 MB), ticket, wt (1 MB),
  // sp (4 KB). prep re-zeroes carry/ticket each launch (graph-replay safe).
  char* ws = (char*)d_ws;
  unsigned long long* carry = (unsigned long long*)ws;         // 8 MB
  int* ticket = (int*)(ws + (8 << 20));
  unsigned short* wt = (unsigned short*)(ws + (8 << 20) + 1024);  // 1 MB
  float* sp = (float*)(ws + (8 << 20) + 1024 + (1 << 20));

  prep_kernel<<<1024, 256, 0, stream>>>(w_in, w_a, a_param, wt, sp,
                                        carry, ticket);
  fused_kernel<<<NBLK, 256, 0, stream>>>(x, wt, sp, b_in, b_a, out,
                                         ticket, carry);
}